// Round 12
// baseline (993.767 us; speedup 1.0000x reference)
//
#include <hip/hip_runtime.h>
#include <stdint.h>

#define DEV static __device__ __forceinline__

typedef float          f32x4  __attribute__((ext_vector_type(4)));
typedef short          bf16x8 __attribute__((ext_vector_type(8)));
typedef unsigned short u16x4  __attribute__((ext_vector_type(4)));
typedef unsigned short u16x8  __attribute__((ext_vector_type(8)));

#define B_   2
#define T_   8192
#define D_   1024
#define H_   8
#define HD_  128
#define N_   128   /* chunks per (b,h) */

DEV float dot4(const float4& a, const float4& b) {
    return a.x * b.x + a.y * b.y + a.z * b.z + a.w * b.w;
}
DEV unsigned short f2bf(float f) {
    union { float f; unsigned u; } v; v.f = f;
    unsigned r = (v.u + 0x7fffu + ((v.u >> 16) & 1u)) >> 16;
    return (unsigned short)r;
}
DEV float bf2f(unsigned short u) {
    union { unsigned u; float f; } v; v.u = ((unsigned)u) << 16;
    return v.f;
}
DEV void cvt4(const float4 v, u16x4* h, u16x4* l) {
    const float* p = (const float*)&v;
    #pragma unroll
    for (int i = 0; i < 4; ++i) {
        unsigned short hv = f2bf(p[i]);
        (*h)[i] = hv;
        (*l)[i] = f2bf(p[i] - bf2f(hv));
    }
}
// LDS-ordering-only barrier (no vmcnt drain).
DEV void bar_lgkm() {
    asm volatile("s_waitcnt lgkmcnt(0)" ::: "memory");
    __builtin_amdgcn_s_barrier();
}
// Swizzled LDS rows of 512B (128 f32); swizzle per 16B unit: unit ^= (row&7).
DEV float4* r512(char* base, int r, int u) {
    return (float4*)(base + (r << 9) + ((u << 4) ^ ((r & 7) << 4)));
}
DEV float ld_sk(char* base, int c, int dk) {
    return *(float*)(base + (c << 9) + ((((dk >> 2) << 4) ^ ((c & 7) << 4)) + ((dk & 3) << 2)));
}

// =====================================================================
// Kernel 0: split — f32 array -> bf16 hi/lo planes (weights).
// =====================================================================
__launch_bounds__(256)
__global__ void split_kernel(const float* __restrict__ src,
                             unsigned short* __restrict__ h,
                             unsigned short* __restrict__ l) {
    size_t base = ((size_t)blockIdx.x * 256 + threadIdx.x) * 8;
    float4 a = *(const float4*)(src + base);
    float4 b = *(const float4*)(src + base + 4);
    u16x4 ah, al, bh, bl;
    cvt4(a, &ah, &al);
    cvt4(b, &bh, &bl);
    *(u16x4*)(h + base)     = ah;
    *(u16x4*)(h + base + 4) = bh;
    *(u16x4*)(l + base)     = al;
    *(u16x4*)(l + base + 4) = bl;
}

// =====================================================================
// Kernel 1: prep
// =====================================================================
__launch_bounds__(256)
__global__ void prep_kernel(const float* __restrict__ X, const float* __restrict__ Wb,
                            unsigned short* __restrict__ khi, unsigned short* __restrict__ klo,
                            float* __restrict__ beta) {
    int bt = blockIdx.x;
    int b = bt >> 13, t = bt & 8191;
    __shared__ float xrow[D_];
    const float* xp = X + (size_t)bt * D_;
    for (int i = threadIdx.x; i < D_; i += 256) xrow[i] = xp[i];
    __syncthreads();
    int w = threadIdx.x >> 6, lane = threadIdx.x & 63;
    for (int h = w; h < H_; h += 4) {
        const float* xh = xrow + h * HD_;
        float a0 = xh[lane], a1 = xh[lane + 64];
        float s = a0 * a0 + a1 * a1;
        #pragma unroll
        for (int off = 32; off > 0; off >>= 1) s += __shfl_xor(s, off);
        float rn = 1.0f / fmaxf(sqrtf(s), 1e-12f);
        const float* wbh = Wb + (size_t)h * D_;
        float bs = 0.f;
        for (int i = lane; i < D_; i += 64) bs += xrow[i] * wbh[i];
        #pragma unroll
        for (int off = 32; off > 0; off >>= 1) bs += __shfl_xor(bs, off);
        float bet = 1.0f / (1.0f + expf(-bs));
        size_t kbase = ((size_t)(b * H_ + h) * T_ + t) * HD_;
        float x0 = a0 * rn, x1 = a1 * rn;
        unsigned short h0 = f2bf(x0), h1 = f2bf(x1);
        khi[kbase + lane]      = h0;
        khi[kbase + lane + 64] = h1;
        klo[kbase + lane]      = f2bf(x0 - bf2f(h0));
        klo[kbase + lane + 64] = f2bf(x1 - bf2f(h1));
        if (lane == 0) beta[(size_t)(b * H_ + h) * T_ + t] = bet;
    }
}

// =====================================================================
// Kernel 2: vproj
// =====================================================================
__launch_bounds__(256, 2)
__global__ void vproj_kernel(const float* __restrict__ X,
                             const unsigned short* __restrict__ Wh,
                             const unsigned short* __restrict__ Wl,
                             const float* __restrict__ beta, float* __restrict__ vb) {
    extern __shared__ char gs[];
    char* AH = gs;
    char* AL = gs + 16384;
    char* BH = gs + 32768;
    char* BL = gs + 49152;
    int bm = blockIdx.x, bn = blockIdx.y;
    int tid = threadIdx.x;
    int w = tid >> 6, lr = tid & 15, lk = (tid & 63) >> 4;
    int wm = w >> 1, wn = w & 1;

    f32x4 acc[4][4];
    #pragma unroll
    for (int i = 0; i < 4; ++i)
        #pragma unroll
        for (int j = 0; j < 4; ++j) acc[i][j] = (f32x4){0.f, 0.f, 0.f, 0.f};

    for (int kt = 0; kt < 16; ++kt) {
        __syncthreads();
        #pragma unroll
        for (int q = 0; q < 8; ++q) {
            int f = tid + q * 256;
            int row = f >> 4, kq = f & 15;
            float4 av = *(const float4*)(X + (size_t)(bm * 128 + row) * D_ + kt * 64 + kq * 4);
            u16x4 ah, al;
            cvt4(av, &ah, &al);
            int off = row * 128 + ((((kq >> 1) ^ (row & 7))) << 4) + ((kq & 1) << 3);
            *(u16x4*)(AH + off) = ah; *(u16x4*)(AL + off) = al;
        }
        #pragma unroll
        for (int q = 0; q < 4; ++q) {
            int f = tid + q * 256;
            int row = f >> 3, u = f & 7;
            size_t go = (size_t)(bn * 128 + row) * D_ + kt * 64 + u * 8;
            int off = row * 128 + ((u ^ (row & 7)) << 4);
            *(u16x8*)(BH + off) = *(const u16x8*)(Wh + go);
            *(u16x8*)(BL + off) = *(const u16x8*)(Wl + go);
        }
        __syncthreads();
        #pragma unroll
        for (int ks = 0; ks < 2; ++ks) {
            bf16x8 aH[4], aL[4], bH[4], bL[4];
            #pragma unroll
            for (int mt = 0; mt < 4; ++mt) {
                int row = wm * 64 + mt * 16 + lr;
                int off = row * 128 + (((ks * 4 + lk) ^ (row & 7)) << 4);
                aH[mt] = *(const bf16x8*)(AH + off);
                aL[mt] = *(const bf16x8*)(AL + off);
            }
            #pragma unroll
            for (int nt = 0; nt < 4; ++nt) {
                int row = wn * 64 + nt * 16 + lr;
                int off = row * 128 + (((ks * 4 + lk) ^ (row & 7)) << 4);
                bH[nt] = *(const bf16x8*)(BH + off);
                bL[nt] = *(const bf16x8*)(BL + off);
            }
            #pragma unroll
            for (int mt = 0; mt < 4; ++mt)
                #pragma unroll
                for (int nt = 0; nt < 4; ++nt) {
                    acc[mt][nt] = __builtin_amdgcn_mfma_f32_16x16x32_bf16(aH[mt], bH[nt], acc[mt][nt], 0, 0, 0);
                    acc[mt][nt] = __builtin_amdgcn_mfma_f32_16x16x32_bf16(aH[mt], bL[nt], acc[mt][nt], 0, 0, 0);
                    acc[mt][nt] = __builtin_amdgcn_mfma_f32_16x16x32_bf16(aL[mt], bH[nt], acc[mt][nt], 0, 0, 0);
                }
        }
    }
    #pragma unroll
    for (int mt = 0; mt < 4; ++mt)
        #pragma unroll
        for (int r = 0; r < 4; ++r) {
            int m = bm * 128 + wm * 64 + mt * 16 + lk * 4 + r;
            int b = m >> 13, t = m & 8191;
            float bet = beta[(size_t)(b * H_ + bn) * T_ + t];
            size_t ob = ((size_t)(b * H_ + bn) * T_ + t) * HD_;
            #pragma unroll
            for (int nt = 0; nt < 4; ++nt)
                vb[ob + wn * 64 + nt * 16 + lr] = acc[mt][nt][r] * bet;
        }
}

// =====================================================================
// Kernel 3: chunk
// =====================================================================
__launch_bounds__(256, 2)
__global__ void chunk_kernel(const unsigned short* __restrict__ khi,
                             const unsigned short* __restrict__ klo,
                             float* __restrict__ vb,
                             const float* __restrict__ beta_g,
                             const float* __restrict__ decay,
                             unsigned short* __restrict__ attn_g,
                             unsigned short* __restrict__ kcdhi_g,
                             unsigned short* __restrict__ kcdlo_g,
                             unsigned short* __restrict__ kdwh_g) {
    extern __shared__ char cs[];
    char*  sk = cs;
    float* sa = (float*)(cs + 32768);
    float* sm = (float*)(cs + 49152);
    __shared__ float sb[64];
    __shared__ float swgt[64];

    int cid = blockIdx.x;
    int bh = cid >> 7, cn = cid & 127;
    int h = bh & 7;
    int tid = threadIdx.x;
    float dec = decay[h];
    float sg = 1.0f / (1.0f + expf(-dec));
    float lg = logf(sg);
    size_t base = (size_t)cid * 8192;

    #pragma unroll
    for (int lq = 0; lq < 4; ++lq) {
        int f = tid + lq * 256;
        int c = f >> 4, u0 = (f & 15) << 1;
        u16x8 hh = *(const u16x8*)(khi + base + (size_t)f * 8);
        u16x8 ll = *(const u16x8*)(klo + base + (size_t)f * 8);
        float4 v0 = {bf2f(hh[0]) + bf2f(ll[0]), bf2f(hh[1]) + bf2f(ll[1]),
                     bf2f(hh[2]) + bf2f(ll[2]), bf2f(hh[3]) + bf2f(ll[3])};
        float4 v1 = {bf2f(hh[4]) + bf2f(ll[4]), bf2f(hh[5]) + bf2f(ll[5]),
                     bf2f(hh[6]) + bf2f(ll[6]), bf2f(hh[7]) + bf2f(ll[7])};
        *r512(sk, c, u0)     = v0;
        *r512(sk, c, u0 + 1) = v1;
    }
    if (tid < 64) {
        float bv = beta_g[(size_t)bh * T_ + cn * 64 + tid];
        sb[tid] = bv;
        swgt[tid] = bv * expf((float)(tid + 1) * lg);
    }
    __syncthreads();

    int bi = tid >> 4, bj = tid & 15;
    float dacc[4][4] = {};
    for (int u = 0; u < 32; ++u) {
        float4 ka[4], kc[4];
        #pragma unroll
        for (int i = 0; i < 4; ++i) ka[i] = *r512(sk, bi * 4 + i, u);
        #pragma unroll
        for (int j = 0; j < 4; ++j) kc[j] = *r512(sk, bj + 16 * j, u);
        #pragma unroll
        for (int i = 0; i < 4; ++i)
            #pragma unroll
            for (int j = 0; j < 4; ++j)
                dacc[i][j] += dot4(ka[i], kc[j]);
    }
    size_t abase = (size_t)cid * 4096;
    #pragma unroll
    for (int i = 0; i < 4; ++i) {
        int gi = bi * 4 + i;
        #pragma unroll
        for (int j = 0; j < 4; ++j) {
            int gj = bj + 16 * j;
            float dv = dacc[i][j];
            float dfac = expf((float)(gi - gj) * lg);
            attn_g[abase + (size_t)gi * 64 + gj] = (gi >= gj) ? f2bf(dv * dfac) : (unsigned short)0;
            sm[gi * 64 + gj] = (gj < gi) ? sb[gi] * dv * dfac : ((gi == gj) ? 1.f : 0.f);
        }
    }
    __syncthreads();

    if (tid < 64) {
        int j = tid;
        for (int i = 0; i < j; ++i) sa[i * 64 + j] = 0.f;
        sa[j * 64 + j] = 1.f;
        for (int i = j + 1; i < 64; ++i) {
            float s = 0.f;
            for (int p = j; p < i; ++p) s += sm[i * 64 + p] * sa[p * 64 + j];
            sa[i * 64 + j] = -s;
        }
    }
    __syncthreads();

    int ti = tid >> 4, te = tid & 15;
    {
        float ko[4][8] = {};
        for (int p = 0; p < 64; ++p) {
            float w = swgt[p];
            float4 k0 = *r512(sk, p, te * 2);
            float4 k1 = *r512(sk, p, te * 2 + 1);
            float kv[8] = {k0.x, k0.y, k0.z, k0.w, k1.x, k1.y, k1.z, k1.w};
            float a0 = sa[(ti * 4 + 0) * 64 + p] * w;
            float a1 = sa[(ti * 4 + 1) * 64 + p] * w;
            float a2 = sa[(ti * 4 + 2) * 64 + p] * w;
            float a3 = sa[(ti * 4 + 3) * 64 + p] * w;
            #pragma unroll
            for (int e = 0; e < 8; ++e) {
                ko[0][e] = fmaf(a0, kv[e], ko[0][e]);
                ko[1][e] = fmaf(a1, kv[e], ko[1][e]);
                ko[2][e] = fmaf(a2, kv[e], ko[2][e]);
                ko[3][e] = fmaf(a3, kv[e], ko[3][e]);
            }
        }
        #pragma unroll
        for (int i = 0; i < 4; ++i) {
            u16x8 hh, ll;
            #pragma unroll
            for (int e = 0; e < 8; ++e) {
                float t = -ko[i][e];
                unsigned short hv = f2bf(t);
                hh[e] = hv;
                ll[e] = f2bf(t - bf2f(hv));
            }
            size_t off = base + (size_t)(ti * 4 + i) * 128 + te * 8;
            *(u16x8*)(kcdhi_g + off) = hh;
            *(u16x8*)(kcdlo_g + off) = ll;
        }
    }

    {
        int dk = tid >> 1, ch = (tid & 1) * 32;
        #pragma unroll
        for (int q = 0; q < 4; ++q) {
            u16x8 th;
            #pragma unroll
            for (int j = 0; j < 8; ++j) {
                int c = ch + q * 8 + j;
                float kv = ld_sk(sk, c, dk) * expf((float)(63 - c) * lg);
                th[j] = f2bf(kv);
            }
            *(u16x8*)(kdwh_g + base + (size_t)dk * 64 + ch + q * 8) = th;
        }
    }
    __syncthreads();

    #pragma unroll
    for (int lq = 0; lq < 8; ++lq) {
        int f = tid + lq * 256;
        int r = f >> 5, u = f & 31;
        *r512(sk, r, u) = ((const float4*)(vb + base))[f];
    }
    __syncthreads();

    {
        float vo[4][8] = {};
        for (int p = 0; p < 64; ++p) {
            float4 v0 = *r512(sk, p, te * 2);
            float4 v1 = *r512(sk, p, te * 2 + 1);
            float vv[8] = {v0.x, v0.y, v0.z, v0.w, v1.x, v1.y, v1.z, v1.w};
            float a0 = sa[(ti * 4 + 0) * 64 + p];
            float a1 = sa[(ti * 4 + 1) * 64 + p];
            float a2 = sa[(ti * 4 + 2) * 64 + p];
            float a3 = sa[(ti * 4 + 3) * 64 + p];
            #pragma unroll
            for (int e = 0; e < 8; ++e) {
                vo[0][e] = fmaf(a0, vv[e], vo[0][e]);
                vo[1][e] = fmaf(a1, vv[e], vo[1][e]);
                vo[2][e] = fmaf(a2, vv[e], vo[2][e]);
                vo[3][e] = fmaf(a3, vv[e], vo[3][e]);
            }
        }
        #pragma unroll
        for (int i = 0; i < 4; ++i) {
            float4 lo = {vo[i][0], vo[i][1], vo[i][2], vo[i][3]};
            float4 hi = {vo[i][4], vo[i][5], vo[i][6], vo[i][7]};
            size_t off = base + (size_t)(ti * 4 + i) * 128 + te * 8;
            *(float4*)(vb + off)     = lo;
            *(float4*)(vb + off + 4) = hi;
        }
    }
}

// =====================================================================
// Shared scan step machinery (v8 numerics; 2-prod M3).
// =====================================================================
#define SCAN_PREFETCH(NCH, fH, fL, atA, vnA)                                          \
    {                                                                                 \
        size_t nb = ((size_t)bh * N_ + (NCH)) * 8192;                                 \
        size_t na = ((size_t)bh * N_ + (NCH)) * 4096;                                 \
        if (grp == 0) {                                                               \
            _Pragma("unroll")                                                         \
            for (int ks = 0; ks < 4; ++ks) {                                          \
                size_t off = nb + (size_t)(cw * 16 + lr) * 128 + ks * 32 + lk * 8;    \
                fH[ks] = *(const bf16x8*)(kcdh + off);                                \
                fL[ks] = *(const bf16x8*)(kcdl + off);                                \
            }                                                                         \
            _Pragma("unroll")                                                         \
            for (int r = 0; r < 4; ++r)                                               \
                vnA[r] = vb[nb + (size_t)(cw * 16 + lk * 4 + r) * 128 + e0 + lr];     \
        } else {                                                                      \
            _Pragma("unroll")                                                         \
            for (int ks = 0; ks < 4; ++ks) {                                          \
                size_t off = nb + (size_t)(cw * 16 + lr) * 128 + ks * 32 + lk * 8;    \
                fH[ks] = *(const bf16x8*)(khi + off);                                 \
                fL[ks] = *(const bf16x8*)(klo + off);                                 \
            }                                                                         \
            _Pragma("unroll")                                                         \
            for (int ks2 = 0; ks2 < 2; ++ks2)                                         \
                atA[ks2] = *(const bf16x8*)(att + na + (size_t)(cw * 16 + lr) * 64 + ks2 * 32 + lk * 8); \
        }                                                                             \
    }

#define SCAN_STEP(CN, LIM, fH, fL, atA, vnA)                                          \
    {                                                                                 \
        size_t cb8 = ((size_t)bh * N_ + (CN)) * 8192;                                 \
        bf16x8 tH[2];                                                                 \
        _Pragma("unroll")                                                             \
        for (int ks2 = 0; ks2 < 2; ++ks2)                                             \
            tH[ks2] = *(const bf16x8*)(kdwh + cb8 + (size_t)(w * 16 + lr) * 64 + ks2 * 32 + lk * 8); \
        {                                                                             \
            u16x4 h4, l4;                                                             \
            _Pragma("unroll")                                                         \
            for (int r = 0; r < 4; ++r) {                                             \
                unsigned short hv = f2bf(Sacc[r]);                                    \
                h4[r] = hv;                                                           \
                l4[r] = f2bf(Sacc[r] - bf2f(hv));                                     \
            }                                                                         \
            int unit = 2 * w + (lk >> 1);                                             \
            int off = lr * 256 + ((unit ^ (lr & 7)) << 4) + ((lk & 1) << 3);          \
            *(u16x4*)(SH + off) = h4;                                                 \
            *(u16x4*)(SL + off) = l4;                                                 \
        }                                                                             \
        bar_lgkm();                                                                   \
        bf16x8 BH[4], BL[4];                                                          \
        _Pragma("unroll")                                                             \
        for (int ks = 0; ks < 4; ++ks) {                                              \
            int off = lr * 256 + (((ks * 4 + lk) ^ (lr & 7)) << 4);                   \
            BH[ks] = *(const bf16x8*)(SH + off);                                      \
            BL[ks] = *(const bf16x8*)(SL + off);                                      \
        }                                                                             \
        f32x4 acc1, acc2;                                                             \
        if (grp == 0) {                                                               \
            acc1 = vnA; acc2 = (f32x4){0.f, 0.f, 0.f, 0.f};                           \
            __builtin_amdgcn_s_setprio(1);                                            \
            _Pragma("unroll")                                                         \
            for (int ks = 0; ks < 2; ++ks) {                                          \
                acc1 = __builtin_amdgcn_mfma_f32_16x16x32_bf16(fH[ks], BH[ks], acc1, 0, 0, 0);       \
                acc2 = __builtin_amdgcn_mfma_f32_16x16x32_bf16(fH[ks+2], BH[ks+2], acc2, 0, 0, 0);   \
                acc1 = __builtin_amdgcn_mfma_f32_16x16x32_bf16(fH[ks], BL[ks], acc1, 0, 0, 0);       \
                acc2 = __builtin_amdgcn_mfma_f32_16x16x32_bf16(fH[ks+2], BL[ks+2], acc2, 0, 0, 0);   \
                acc1 = __builtin_amdgcn_mfma_f32_16x16x32_bf16(fL[ks], BH[ks], acc1, 0, 0, 0);       \
                acc2 = __builtin_amdgcn_mfma_f32_16x16x32_bf16(fL[ks+2], BH[ks+2], acc2, 0, 0, 0);   \
            }                                                                         \
            __builtin_amdgcn_s_setprio(0);                                            \
            u16x4 h4, l4;                                                             \
            _Pragma("unroll")                                                         \
            for (int r = 0; r < 4; ++r) {                                             \
                float vv = acc1[r] + acc2[r];                                         \
                unsigned short hv = f2bf(vv);                                         \
                h4[r] = hv; l4[r] = f2bf(vv - bf2f(hv));                              \
            }                                                                         \
            int cu = 2 * cw + (lk >> 1);                                              \
            int off = lr * 128 + ((cu ^ (lr & 7)) << 4) + ((lk & 1) << 3);            \
            *(u16x4*)(VH + off) = h4;  *(u16x4*)(VL + off) = l4;                      \
        } else {                                                                      \
            acc1 = (f32x4){0.f, 0.f, 0.f, 0.f}; acc2 = acc1;                          \
            __builtin_amdgcn_s_setprio(1);                                            \
            _Pragma("unroll")                                                         \
            for (int ks = 0; ks < 2; ++ks) {                                          \
                acc1 = __builtin_amdgcn_mfma_f32_16x16x32_bf16(fH[ks], BH[ks], acc1, 0, 0, 0);       \
                acc2 = __builtin_amdgcn_mfma_f32_16x16x32_bf16(fH[ks+2], BH[ks+2], acc2, 0, 0, 0);   \
                acc1 = __builtin_amdgcn_mfma_f32_16x16x32_bf16(fH[ks], BL[ks], acc1, 0, 0, 0);       \
                acc2 = __builtin_amdgcn_mfma_f32_16x16x32_bf16(fH[ks+2], BL[ks+2], acc2, 0, 0, 0);   \
                acc1 = __builtin_amdgcn_mfma_f32_16x16x32_bf16(fL[ks], BH[ks], acc1, 0, 0, 0);       \
                acc2 = __builtin_amdgcn_mfma_f32_16x16x32_bf16(fL[ks+2], BH[ks+2], acc2, 0, 0, 0);   \
            }                                                                         \
            __builtin_amdgcn_s_setprio(0);                                            \
        }                                                                             \
        bar_lgkm();                                                                   \
        bf16x8 VHf[2], VLf[2];                                                        \
        _Pragma("unroll")                                                             \
        for (int ks2 = 0; ks2 < 2; ++ks2) {                                           \
            int off = lr * 128 + (((ks2 * 4 + lk) ^ (lr & 7)) << 4);                  \
            VHf[ks2] = *(const bf16x8*)(VH + off);                                    \
            VLf[ks2] = *(const bf16x8*)(VL + off);                                    \
        }                                                                             \
        if (grp == 1) {                                                               \
            f32x4 om;                                                                 \
            _Pragma("unroll")                                                         \
            for (int r = 0; r < 4; ++r) om[r] = (acc1[r] + acc2[r]) * dev4[r];        \
            _Pragma("unroll")                                                         \
            for (int ks2 = 0; ks2 < 2; ++ks2) {                                       \
                om = __builtin_amdgcn_mfma_f32_16x16x32_bf16(atA[ks2], VHf[ks2], om, 0, 0, 0);  \
                om = __builtin_amdgcn_mfma_f32_16x16x32_bf16(atA[ks2], VLf[ks2], om, 0, 0, 0);  \
            }                                                                         \
            _Pragma("unroll")                                                         \
            for (int r = 0; r < 4; ++r)                                               \
                vb[cb8 + (size_t)(cw * 16 + lk * 4 + r) * 128 + e0 + lr] = om[r];     \
        }                                                                             \
        if ((CN) + 2 < (LIM)) SCAN_PREFETCH((CN) + 2, fH, fL, atA, vnA)               \
        {                                                                             \
            _Pragma("unroll")                                                         \
            for (int r = 0; r < 4; ++r) Sacc[r] *= g64;                               \
            f32x4 tmp = (f32x4){0.f, 0.f, 0.f, 0.f};                                  \
            __builtin_amdgcn_s_setprio(1);                                            \
            Sacc = __builtin_amdgcn_mfma_f32_16x16x32_bf16(tH[0], VHf[0], Sacc, 0, 0, 0);  \
            tmp  = __builtin_amdgcn_mfma_f32_16x16x32_bf16(tH[1], VHf[1], tmp,  0, 0, 0);  \
            Sacc = __builtin_amdgcn_mfma_f32_16x16x32_bf16(tH[0], VLf[0], Sacc, 0, 0, 0);  \
            tmp  = __builtin_amdgcn_mfma_f32_16x16x32_bf16(tH[1], VLf[1], tmp,  0, 0, 0);  \
            __builtin_amdgcn_s_setprio(0);                                            \
            _Pragma("unroll")                                                         \
            for (int r = 0; r < 4; ++r) Sacc[r] += tmp[r];                            \
        }                                                                             \
    }

// ---- A/B-run reduced step (no o, no att; A-mode: vnA==0) ----
#define AB_PREFETCH(NCH, fH, fL, vnA)                                                 \
    if (grp == 0) {                                                                   \
        size_t nb = ((size_t)bh * N_ + (NCH)) * 8192;                                 \
        _Pragma("unroll")                                                             \
        for (int ks = 0; ks < 4; ++ks) {                                              \
            size_t off = nb + (size_t)(cw * 16 + lr) * 128 + ks * 32 + lk * 8;        \
            fH[ks] = *(const bf16x8*)(kcdh + off);                                    \
            fL[ks] = *(const bf16x8*)(kcdl + off);                                    \
        }                                                                             \
        if (!isA) {                                                                   \
            _Pragma("unroll")                                                         \
            for (int r = 0; r < 4; ++r)                                               \
                vnA[r] = vb[nb + (size_t)(cw * 16 + lk * 4 + r) * 128 + e0 + lr];     \
        }                                                                             \
    }

#define AB_STEP(CN, LIM, fH, fL, vnA)                                                 \
    {                                                                                 \
        size_t cb8 = ((size_t)bh * N_ + (CN)) * 8192;                                 \
        bf16x8 tH[2];                                                                 \
        _Pragma("unroll")                                                             \
        for (int ks2 = 0; ks2 < 2; ++ks2)                                             \
            tH[ks2] = *(const bf16x8*)(kdwh + cb8 + (size_t)(w * 16 + lr) * 64 + ks2 * 32 + lk * 8); \
        {                                                                             \
            u16x4 h4, l4;                                                             \
            _Pragma("unroll")                                                         \
            for (int r = 0; r < 4; ++r) {                                             \
                unsigned short hv = f2bf(Sacc[r]);                                    \
                h4[r] = hv;                                                           \
                l4[r] = f2bf(Sacc[r] - bf2f(hv));                                     \
            }                                                                         \
            int unit = 2 * w + (lk >> 1);                                             \
            int off = lr * 256 + ((unit ^ (lr & 7)) << 4) + ((lk & 1) << 3);          \
            *(u16x4*)(SH + off) = h4;                                                 \
            *(u16x4*)(SL + off) = l4;                                                 \
        }                                                                             \
        bar_lgkm();                                                                   \
        if (grp == 0) {                                                               \
            bf16x8 BH[4], BL[4];                                                      \
            _Pragma("unroll")                                                         \
            for (int ks = 0; ks < 4; ++ks) {                                          \
                int off = lr * 256 + (((ks * 4 + lk) ^ (lr & 7)) << 4);               \
                BH[ks] = *(const bf16x8*)(SH + off);                                  \
                BL[ks] = *(const bf16x8*)(SL + off);                                  \
            }                                                                         \
            f32x4 acc1 = vnA, acc2 = (f32x4){0.f, 0.f, 0.f, 0.f};                     \
            __builtin_amdgcn_s_setprio(1);                                            \
            _Pragma("unroll")                                                         \
            for (int ks = 0; ks < 2; ++ks) {                                          \
                acc1 = __builtin_amdgcn_mfma_f32_16x16x32_bf16(fH[ks], BH[ks], acc1, 0, 0, 0);       \
                acc2 = __builtin_amdgcn_mfma_f32_16x16x32_bf16(fH[ks+2], BH[ks+2], acc2, 0, 0, 0);   \
                acc1 = __builtin_amdgcn_mfma_f32_16x16x32_bf16(fH[ks], BL[ks], acc1, 0, 0, 0);       \
                acc2 = __builtin_amdgcn_mfma_f32_16x16x32_bf16(fH[ks+2], BL[ks+2], acc2, 0, 0, 0);   \
                acc1 = __builtin_amdgcn_mfma_f32_16x16x32_bf16(fL[ks], BH[ks], acc1, 0, 0, 0);       \
                acc2 = __builtin_amdgcn_mfma_f32_16x16x32_bf16(fL[ks+2], BH[ks+2], acc2, 0, 0, 0);   \
            }                                                                         \
            __builtin_amdgcn_s_setprio(0);                                            \
            u16x4 h4, l4;                                                             \
            _Pragma("unroll")                                                         \
            for (int r = 0; r < 4; ++r) {                                             \
                float vv = acc1[r] + acc2[r];                                         \
                unsigned short hv = f2bf(vv);                                         \
                h4[r] = hv; l4[r] = f2bf(vv - bf2f(hv));                              \
            }                                                                         \
            int cu = 2 * cw + (lk >> 1);                                              \
            int off = lr * 128 + ((cu ^ (lr & 7)) << 4) + ((lk & 1) << 3);            \
            *(u16x4*)(VH + off) = h4;  *(u16x4*)(VL + off) = l4;                      \
        }                                                                             \
        bar_lgkm();                                                                   \
        bf16x8 VHf[2], VLf[2];                                                        \
        _Pragma("unroll")                                                             \
        for (int ks2 = 0; ks2 < 2; ++ks2) {                                           \
            int off = lr * 128 + (((ks2 * 4 + lk) ^ (lr & 7)) << 4);                  \
            VHf[ks2] = *(const bf16x8*)(VH + off);                                    \
            VLf[ks2] = *(const bf16x8*)(VL + off);                                    \
        }                                                                             \
        if ((CN) + 2 < (LIM)) AB_PREFETCH((CN) + 2, fH, fL, vnA)                      \
        {                                                                             \
            _Pragma("unroll")                                                         \
            for (int r = 0; r < 4; ++r) Sacc[r] *= g64;                               \
            f32x4 tmp = (f32x4){0.f, 0.f, 0.f, 0.f};                                  \
            __builtin_amdgcn_s_setprio(1);                                            \
            Sacc = __builtin_amdgcn_mfma_f32_16x16x32_bf16(tH[0], VHf[0], Sacc, 0, 0, 0);  \
            tmp  = __builtin_amdgcn_mfma_f32_16x16x32_bf16(tH[1], VHf[1], tmp,  0, 0, 0);  \
            Sacc = __builtin_amdgcn_mfma_f32_16x16x32_bf16(tH[0], VLf[0], Sacc, 0, 0, 0);  \
            tmp  = __builtin_amdgcn_mfma_f32_16x16x32_bf16(tH[1], VLf[1], tmp,  0, 0, 0);  \
            __builtin_amdgcn_s_setprio(0);                                            \
            _Pragma("unroll")                                                         \
            for (int r = 0; r < 4; ++r) Sacc[r] += tmp[r];                            \
        }                                                                             \
    }

// =====================================================================
// Kernel 4f: scan fallback (v8) — full 128-chunk sequential scan.
// =====================================================================
__launch_bounds__(512, 1)
__global__ void scan_kernel(const unsigned short* __restrict__ khi,
                            const unsigned short* __restrict__ klo,
                            float* __restrict__ vb,
                            const unsigned short* __restrict__ kcdh,
                            const unsigned short* __restrict__ kcdl,
                            const unsigned short* __restrict__ att,
                            const unsigned short* __restrict__ kdwh,
                            const float* __restrict__ decay) {
    __shared__ char SH[4096];
    __shared__ char SL[4096];
    __shared__ char VH[2048];
    __shared__ char VL[2048];

    int bid = blockIdx.x;
    int bh = ((bid >> 6) << 3) + (bid & 7);
    int strip = (bid >> 3) & 7;
    int e0 = strip * 16;
    int tid = threadIdx.x;
    int w = tid >> 6, l = tid & 63, lr = l & 15, lk = l >> 4;
    int grp = w >> 2, cw = w & 3;
    float dec = decay[bh & 7];
    float sg = 1.0f / (1.0f + expf(-dec));
    float lg = logf(sg);
    float g64 = expf(64.f * lg);
    float dev4[4];
    #pragma unroll
    for (int r = 0; r < 4; ++r)
        dev4[r] = expf((float)(cw * 16 + lk * 4 + r + 1) * lg);

    f32x4 Sacc = (f32x4){0.f, 0.f, 0.f, 0.f};
    bf16x8 fHa[4], fLa[4], atAa[2];
    bf16x8 fHb[4], fLb[4], atAb[2];
    f32x4 vnAa, vnAb;

    SCAN_PREFETCH(0, fHa, fLa, atAa, vnAa)
    SCAN_PREFETCH(1, fHb, fLb, atAb, vnAb)
    for (int cn = 0; cn < N_; cn += 2) {
        SCAN_STEP(cn,     N_, fHa, fLa, atAa, vnAa)
        SCAN_STEP(cn + 1, N_, fHb, fLb, atAb, vnAb)
    }
}

// =====================================================================
// Kernel 4a: phaseAB — segment maps. grid 16bh x 13 x 8 strips = 1664.
// slot<6: A-run (seg=slot+1, S0=I, v'=0) -> Aseg; else B-run (seg=slot-6,
// S0=0, real v') -> Bseg.
// =====================================================================
__launch_bounds__(512, 1)
__global__ void phaseAB_kernel(const unsigned short* __restrict__ khi,   // unused, kept for symmetry
                               const float* __restrict__ vb,
                               const unsigned short* __restrict__ kcdh,
                               const unsigned short* __restrict__ kcdl,
                               const unsigned short* __restrict__ kdwh,
                               const float* __restrict__ decay,
                               float* __restrict__ Aseg,
                               float* __restrict__ Bseg) {
    __shared__ char SH[4096];
    __shared__ char SL[4096];
    __shared__ char VH[2048];
    __shared__ char VL[2048];

    int bid = blockIdx.x;
    int strip = bid & 7;
    int r2 = bid >> 3;
    int sl = r2 % 13;
    int bh = r2 / 13;
    bool isA = sl < 6;
    int seg = isA ? (sl + 1) : (sl - 6);
    int c0 = seg * 16;
    int e0 = strip * 16;
    int tid = threadIdx.x;
    int w = tid >> 6, l = tid & 63, lr = l & 15, lk = l >> 4;
    int grp = w >> 2, cw = w & 3;
    float dec = decay[bh & 7];
    float sg = 1.0f / (1.0f + expf(-dec));
    float lg = logf(sg);
    float g64 = expf(64.f * lg);

    f32x4 Sacc;
    #pragma unroll
    for (int r = 0; r < 4; ++r)
        Sacc[r] = (isA && (w * 16 + lk * 4 + r) == (e0 + lr)) ? 1.f : 0.f;

    bf16x8 fHa[4], fLa[4], fHb[4], fLb[4];
    f32x4 vnAa = (f32x4){0.f, 0.f, 0.f, 0.f};
    f32x4 vnAb = (f32x4){0.f, 0.f, 0.f, 0.f};

    AB_PREFETCH(c0, fHa, fLa, vnAa)
    AB_PREFETCH(c0 + 1, fHb, fLb, vnAb)
    for (int cn = c0; cn < c0 + 16; cn += 2) {
        AB_STEP(cn,     c0 + 16, fHa, fLa, vnAa)
        AB_STEP(cn + 1, c0 + 16, fHb, fLb, vnAb)
    }
    float* dst = isA ? (Aseg + ((size_t)bh * 6 + (seg - 1)) * 16384)
                     : (Bseg + ((size_t)bh * 7 + seg) * 16384);
    #pragma unroll
    for (int r = 0; r < 4; ++r)
        dst[(size_t)(w * 16 + lk * 4 + r) * 128 + e0 + lr] = Sacc[r];
}

// =====================================================================
// Kernel 4b: phaseB — compose E_{s+1}=A_s E_s + B_s in place over Bseg.
// grid 16bh x 8 strips = 128 blocks x 512 thr, dyn LDS 72KB.
// =====================================================================
__launch_bounds__(512, 1)
__global__ void phaseB_kernel(const float* __restrict__ Aseg,
                              float* __restrict__ Bseg) {
    extern __shared__ char ps[];
    char* AH = ps;              // [128 rows][128 k] bf16 swz, 32KB
    char* AL = ps + 32768;
    char* SH = ps + 65536;      // E^T hi [e:16][dk:128], 4KB
    char* SL = ps + 69632;

    int bid = blockIdx.x;
    int strip = bid & 7;
    int bh = bid >> 3;
    int e0 = strip * 16;
    int tid = threadIdx.x;
    int w = tid >> 6, l = tid & 63, lr = l & 15, lk = l >> 4;

    // Eacc = E_1 = Bseg[0] strip
    f32x4 Eacc;
    {
        const float* E0 = Bseg + ((size_t)bh * 7) * 16384;
        #pragma unroll
        for (int r = 0; r < 4; ++r)
            Eacc[r] = E0[(size_t)(w * 16 + lk * 4 + r) * 128 + e0 + lr];
    }

    for (int s = 1; s <= 6; ++s) {
        __syncthreads();   // protect previous iteration's LDS reads
        // publish Eacc hi/lo to SH/SL  (E^T[e][dk])
        {
            u16x4 h4, l4;
            #pragma unroll
            for (int r = 0; r < 4; ++r) {
                unsigned short hv = f2bf(Eacc[r]);
                h4[r] = hv;
                l4[r] = f2bf(Eacc[r] - bf2f(hv));
            }
            int unit = 2 * w + (lk >> 1);
            int off = lr * 256 + ((unit ^ (lr & 7)) << 4) + ((lk & 1) << 3);
            *(u16x4*)(SH + off) = h4;
            *(u16x4*)(SL + off) = l4;
        }
        // stage A_s -> AH/AL (f32 -> hi/lo)
        const float* Ag = Aseg + ((size_t)bh * 6 + (s - 1)) * 16384;
        #pragma unroll
        for (int q = 0; q < 8; ++q) {
            int f = tid + q * 512;        // 0..4095 float4s
            int row = f >> 5, i4 = f & 31;
            float4 av = ((const float4*)Ag)[f];
            u16x4 ah, al;
            cvt4(av, &ah, &al);
            int off = row * 256 + ((((i4 >> 1) ^ (row & 7))) << 4) + ((i4 & 1) << 3);
            *(u16x4*)(AH + off) = ah;
            *(u16x4*)(AL + off) = al;
        }
        __syncthreads();
        // frags + MFMA: Eacc_new = A_s @ E + B_s
        const float* Bg = Bseg + ((size_t)bh * 7 + s) * 16384;
        f32x4 C;
        #pragma unroll
        for (int r = 0; r < 4; ++r)
            C[r] = Bg[(size_t)(w * 16 + lk * 4 + r) * 128 + e0 + lr];
        #pragma unroll
        for (int ks = 0; ks < 4; ++ks) {
            int arow = w * 16 + lr;
            int aoff = arow * 256 + (((ks * 4 + lk) ^ (arow & 7)) << 4);
            bf16x8 aH = *(const bf16x8*)(AH + aoff);
            bf16x8 aL = *(const bf16x8*)(AL + aoff);
            int boff = lr * 256 + (((ks * 4 + lk) ^ (lr & 7)) << 4);
            bf16x8 bH = *(const bf16x8*)(SH + boff);
            bf16x8 bL = *(const bf16x8*)(SL + boff);
            C = __builtin_amdgcn_mfma_f32_16x16x32_bf16(aH, bH, C, 0, 0, 0);
            C = __builtin_amdgcn_mfma_f32_16x16x32_bf16(aH, bL, C, 0, 0, 0);
            C = __builtin_amdgcn_mfma_f32_16x16x32_bf16(aL, bH, C, 0, 0, 0);
        }
        Eacc = C;
        // store E_{s+1} over Bseg slot s (own strip only)
        float* Bo = Bseg + ((size_t)bh * 7 + s) * 16384;
        #pragma unroll
        for (int r = 0; r < 4; ++r)
            Bo[(size_t)(w * 16 + lk * 4 + r) * 128 + e0 + lr] = Eacc[r];
    }
}

// =====================================================================
// Kernel 4c: phaseC — per-segment 16-chunk scan with entry state, o out.
// grid 16bh x 8seg x 8strips = 1024 blocks x 512 thr.
// =====================================================================
__launch_bounds__(512, 1)
__global__ void phaseC_kernel(const unsigned short* __restrict__ khi,
                              const unsigned short* __restrict__ klo,
                              float* __restrict__ vb,
                              const unsigned short* __restrict__ kcdh,
                              const unsigned short* __restrict__ kcdl,
                              const unsigned short* __restrict__ att,
                              const unsigned short* __restrict__ kdwh,
                              const float* __restrict__ decay,
                              const float* __restrict__ Eseg) {   // = Bseg base
    __shared__ char SH[4096];
    __shared__ char SL[4096];
    __shared__ char VH[2048];
    __shared__ char VL[2048];

    int bid = blockIdx.x;
    int strip = bid & 7;
    int seg = (bid >> 3) & 7;
    int bh = bid >> 6;
    int c0 = seg * 16;
    int e0 = strip * 16;
    int tid = threadIdx.x;
    int w = tid >> 6, l = tid & 63, lr = l & 15, lk = l >> 4;
    int grp = w >> 2, cw = w & 3;
    float dec = decay[bh & 7];
    float sg = 1.0f / (1.0f + expf(-dec));
    float lg = logf(sg);
    float g64 = expf(64.f * lg);
    float dev4[4];
    #pragma unroll
    for (int r = 0; r < 4; ++r)
        dev4[r] = expf((float)(cw * 16 + lk * 4 + r + 1) * lg);

    f32x4 Sacc;
    if (seg == 0) {
        Sacc = (f32x4){0.f, 0.f, 0.f, 0.f};
    } else {
        const float* E = Eseg + ((size_t)bh * 7 + seg - 1) * 16384;
        #pragma unroll
        for (int r = 0; r < 4; ++r)
            Sacc[r] = E[(size_t)(w * 16 + lk * 4 + r) * 128 + e0 + lr];
    }

    bf16x8 fHa[4], fLa[4], atAa[2];
    bf16x8 fHb[4], fLb[4], atAb[2];
    f32x4 vnAa, vnAb;

    SCAN_PREFETCH(c0, fHa, fLa, atAa, vnAa)
    SCAN_PREFETCH(c0 + 1, fHb, fLb, atAb, vnAb)
    for (int cn = c0; cn < c0 + 16; cn += 2) {
        SCAN_STEP(cn,     c0 + 16, fHa, fLa, atAa, vnAa)
        SCAN_STEP(cn + 1, c0 + 16, fHb, fLb, atAb, vnAb)
    }
}

// =====================================================================
// Kernel 5: final
// =====================================================================
__launch_bounds__(256, 2)
__global__ void final_kernel(const float* __restrict__ X,
                             const unsigned short* __restrict__ Wh,
                             const unsigned short* __restrict__ Wl,
                             const float* __restrict__ OB, float* __restrict__ out) {
    extern __shared__ char gs[];
    char* AH = gs;
    char* AL = gs + 16384;
    char* BH = gs + 32768;
    char* BL = gs + 49152;
    int bm = blockIdx.x, bn = blockIdx.y;
    int tid = threadIdx.x;
    int w = tid >> 6, lr = tid & 15, lk = (tid & 63) >> 4;
    int wm = w >> 1, wn = w & 1;

    f32x4 acc[4][4];
    #pragma unroll
    for (int i = 0; i < 4; ++i)
        #pragma unroll
        for (int j = 0; j < 4; ++j) acc[i][j] = (f32x4){0.f, 0.f, 0.f, 0.f};

    for (int kt = 0; kt < 16; ++kt) {
        int hh = kt >> 1, e0g = (kt & 1) * 64;
        __syncthreads();
        #pragma unroll
        for (int q = 0; q < 8; ++q) {
            int f = tid + q * 256;
            int row = f >> 4, kq = f & 15;
            int m = bm * 128 + row;
            int b = m >> 13, t = m & 8191;
            float4 av = *(const float4*)(OB + (((size_t)(b * H_ + hh) * T_ + t) << 7) + e0g + kq * 4);
            u16x4 ah, al;
            cvt4(av, &ah, &al);
            int off = row * 128 + ((((kq >> 1) ^ (row & 7))) << 4) + ((kq & 1) << 3);
            *(u16x4*)(AH + off) = ah; *(u16x4*)(AL + off) = al;
        }
        #pragma unroll
        for (int q = 0; q < 4; ++q) {
            int f = tid + q * 256;
            int row = f >> 3, u = f & 7;
            size_t go = (size_t)(bn * 128 + row) * D_ + kt * 64 + u * 8;
            int off = row * 128 + ((u ^ (row & 7)) << 4);
            *(u16x8*)(BH + off) = *(const u16x8*)(Wh + go);
            *(u16x8*)(BL + off) = *(const u16x8*)(Wl + go);
        }
        __syncthreads();
        #pragma unroll
        for (int ks = 0; ks < 2; ++ks) {
            bf16x8 aH[4], aL[4], bH[4], bL[4];
            #pragma unroll
            for (int mt = 0; mt < 4; ++mt) {
                int row = wm * 64 + mt * 16 + lr;
                int off = row * 128 + (((ks * 4 + lk) ^ (row & 7)) << 4);
                aH[mt] = *(const bf16x8*)(AH + off);
                aL[mt] = *(const bf16x8*)(AL + off);
            }
            #pragma unroll
            for (int nt = 0; nt < 4; ++nt) {
                int row = wn * 64 + nt * 16 + lr;
                int off = row * 128 + (((ks * 4 + lk) ^ (row & 7)) << 4);
                bH[nt] = *(const bf16x8*)(BH + off);
                bL[nt] = *(const bf16x8*)(BL + off);
            }
            #pragma unroll
            for (int mt = 0; mt < 4; ++mt)
                #pragma unroll
                for (int nt = 0; nt < 4; ++nt) {
                    acc[mt][nt] = __builtin_amdgcn_mfma_f32_16x16x32_bf16(aH[mt], bH[nt], acc[mt][nt], 0, 0, 0);
                    acc[mt][nt] = __builtin_amdgcn_mfma_f32_16x16x32_bf16(aH[mt], bL[nt], acc[mt][nt], 0, 0, 0);
                    acc[mt][nt] = __builtin_amdgcn_mfma_f32_16x16x32_bf16(aL[mt], bH[nt], acc[mt][nt], 0, 0, 0);
                }
        }
    }
    #pragma unroll
    for (int mt = 0; mt < 4; ++mt)
        #pragma unroll
        for (int r = 0; r < 4; ++r) {
            int m = bm * 128 + wm * 64 + mt * 16 + lk * 4 + r;
            size_t xo = (size_t)m * D_ + bn * 128;
            #pragma unroll
            for (int nt = 0; nt < 4; ++nt) {
                int n = wn * 64 + nt * 16 + lr;
                out[xo + n] = X[xo + n] + acc[mt][nt][r];
            }
        }
}

// =====================================================================
extern "C" void kernel_launch(void* const* d_in, const int* in_sizes, int n_in,
                              void* d_out, int out_size, void* d_ws, size_t ws_size,
                              hipStream_t stream) {
    const float* X   = (const float*)d_in[0];
    const float* Ww  = (const float*)d_in[1];
    const float* Wr  = (const float*)d_in[2];
    const float* Wb  = (const float*)d_in[3];
    const float* dec = (const float*)d_in[4];

    // workspace layout (bytes). Base = 252,182,528 (proven).
    char* ws = (char*)d_ws;
    unsigned short* khi  = (unsigned short*)(ws);                 // 32MB [c][dk] hi
    unsigned short* klo  = (unsigned short*)(ws + 33554432);      // 32MB
    float*          vb   = (float*)(ws + 67108864);               // 64MB  v -> v' -> o (f32)
    unsigned short* kcdh = (unsigned short*)(ws + 134217728);     // 32MB
    unsigned short* kcdl = (unsigned short*)(ws + 167772160);     // 32MB
    unsigned short* attn = (unsigned short*)(ws + 201326592);     // 16MB
    float*          beta = (float*)(ws + 218103808);              // 0.5MB
    unsigned short* kdwh = (unsigned short*)(ws + 218628096);     // 32MB [dk][c]*gamma hi
    // parallel-scan segment buffers (13 MB beyond base; guarded)
    float*          Aseg = (float*)(ws + 252182528);              // 16bh x 6 x 64KB = 6MB
    float*          Bseg = (float*)(ws + 252182528 + 6291456);    // 16bh x 7 x 64KB = 7MB
    const bool      par  = (ws_size >= 265814016ull);
    if (ws_size < 252182528ull) return;

    // Transient weight-split regions (in dead buffers at time of use).
    unsigned short* Wwh = (unsigned short*)(ws + 134217728);      // 2MB (kcd region, pre-chunk)
    unsigned short* Wwl = (unsigned short*)(ws + 136314880);      // 2MB
    unsigned short* Wrh = (unsigned short*)(ws + 201326592);      // 2MB (attn region, post-scan)
    unsigned short* Wrl = (unsigned short*)(ws + 203423744);      // 2MB

    hipFuncSetAttribute((const void*)vproj_kernel, hipFuncAttributeMaxDynamicSharedMemorySize, 65536);
    hipFuncSetAttribute((const void*)chunk_kernel, hipFuncAttributeMaxDynamicSharedMemorySize, 65536);
    hipFuncSetAttribute((const void*)phaseB_kernel, hipFuncAttributeMaxDynamicSharedMemorySize, 73728);
    hipFuncSetAttribute((const void*)final_kernel, hipFuncAttributeMaxDynamicSharedMemorySize, 65536);

    hipLaunchKernelGGL(prep_kernel, dim3(B_ * T_), dim3(256), 0, stream, X, Wb, khi, klo, beta);
    hipLaunchKernelGGL(split_kernel, dim3(512), dim3(256), 0, stream, Ww, Wwh, Wwl);
    hipLaunchKernelGGL(vproj_kernel, dim3(128, 8), dim3(256), 65536, stream, X, Wwh, Wwl, beta, vb);
    hipLaunchKernelGGL(chunk_kernel, dim3(B_ * H_ * N_), dim3(256), 65536, stream,
                       khi, klo, vb, beta, dec, attn, kcdh, kcdl, kdwh);
    if (par) {
        hipLaunchKernelGGL(phaseAB_kernel, dim3(1664), dim3(512), 0, stream,
                           khi, vb, kcdh, kcdl, kdwh, dec, Aseg, Bseg);
        hipLaunchKernelGGL(phaseB_kernel, dim3(128), dim3(512), 73728, stream, Aseg, Bseg);
        hipLaunchKernelGGL(phaseC_kernel, dim3(1024), dim3(512), 0, stream,
                           khi, klo, vb, kcdh, kcdl, attn, kdwh, dec, Bseg);
    } else {
        hipLaunchKernelGGL(scan_kernel, dim3(128), dim3(512), 0, stream,
                           khi, klo, vb, kcdh, kcdl, attn, kdwh, dec);
    }
    hipLaunchKernelGGL(split_kernel, dim3(512), dim3(256), 0, stream, Wr, Wrh, Wrl);
    hipLaunchKernelGGL(final_kernel, dim3(128, 8), dim3(256), 65536, stream, X, Wrh, Wrl, vb, (float*)d_out);
}

// Round 13
// 944.894 us; speedup vs baseline: 1.0517x; 1.0517x over previous
//
#include <hip/hip_runtime.h>
#include <stdint.h>

#define DEV static __device__ __forceinline__

typedef float          f32x4  __attribute__((ext_vector_type(4)));
typedef short          bf16x8 __attribute__((ext_vector_type(8)));
typedef unsigned short u16x4  __attribute__((ext_vector_type(4)));
typedef unsigned short u16x8  __attribute__((ext_vector_type(8)));

#define B_   2
#define T_   8192
#define D_   1024
#define H_   8
#define HD_  128
#define N_   128   /* chunks per (b,h) */

DEV unsigned short f2bf(float f) {
    union { float f; unsigned u; } v; v.f = f;
    unsigned r = (v.u + 0x7fffu + ((v.u >> 16) & 1u)) >> 16;
    return (unsigned short)r;
}
DEV float bf2f(unsigned short u) {
    union { unsigned u; float f; } v; v.u = ((unsigned)u) << 16;
    return v.f;
}
DEV void cvt4(const float4 v, u16x4* h, u16x4* l) {
    const float* p = (const float*)&v;
    #pragma unroll
    for (int i = 0; i < 4; ++i) {
        unsigned short hv = f2bf(p[i]);
        (*h)[i] = hv;
        (*l)[i] = f2bf(p[i] - bf2f(hv));
    }
}
// LDS-ordering-only barrier (no vmcnt drain).
DEV void bar_lgkm() {
    asm volatile("s_waitcnt lgkmcnt(0)" ::: "memory");
    __builtin_amdgcn_s_barrier();
}
// Swizzled LDS rows of 512B (128 f32); swizzle per 16B unit: unit ^= (row&7).
DEV float4* r512(char* base, int r, int u) {
    return (float4*)(base + (r << 9) + ((u << 4) ^ ((r & 7) << 4)));
}
DEV float ld_sk(char* base, int c, int dk) {
    return *(float*)(base + (c << 9) + ((((dk >> 2) << 4) ^ ((c & 7) << 4)) + ((dk & 3) << 2)));
}

// =====================================================================
// Kernel 0: split — f32 array -> bf16 hi/lo planes (weights).
// =====================================================================
__launch_bounds__(256)
__global__ void split_kernel(const float* __restrict__ src,
                             unsigned short* __restrict__ h,
                             unsigned short* __restrict__ l) {
    size_t base = ((size_t)blockIdx.x * 256 + threadIdx.x) * 8;
    float4 a = *(const float4*)(src + base);
    float4 b = *(const float4*)(src + base + 4);
    u16x4 ah, al, bh, bl;
    cvt4(a, &ah, &al);
    cvt4(b, &bh, &bl);
    *(u16x4*)(h + base)     = ah;
    *(u16x4*)(h + base + 4) = bh;
    *(u16x4*)(l + base)     = al;
    *(u16x4*)(l + base + 4) = bl;
}

// =====================================================================
// Kernel 1: prep — L2-normalized k per head -> bf16 hi/lo [c][dk]; beta.
// =====================================================================
__launch_bounds__(256)
__global__ void prep_kernel(const float* __restrict__ X, const float* __restrict__ Wb,
                            unsigned short* __restrict__ khi, unsigned short* __restrict__ klo,
                            float* __restrict__ beta) {
    int bt = blockIdx.x;
    int b = bt >> 13, t = bt & 8191;
    __shared__ float xrow[D_];
    const float* xp = X + (size_t)bt * D_;
    for (int i = threadIdx.x; i < D_; i += 256) xrow[i] = xp[i];
    __syncthreads();
    int w = threadIdx.x >> 6, lane = threadIdx.x & 63;
    for (int h = w; h < H_; h += 4) {
        const float* xh = xrow + h * HD_;
        float a0 = xh[lane], a1 = xh[lane + 64];
        float s = a0 * a0 + a1 * a1;
        #pragma unroll
        for (int off = 32; off > 0; off >>= 1) s += __shfl_xor(s, off);
        float rn = 1.0f / fmaxf(sqrtf(s), 1e-12f);
        const float* wbh = Wb + (size_t)h * D_;
        float bs = 0.f;
        for (int i = lane; i < D_; i += 64) bs += xrow[i] * wbh[i];
        #pragma unroll
        for (int off = 32; off > 0; off >>= 1) bs += __shfl_xor(bs, off);
        float bet = 1.0f / (1.0f + expf(-bs));
        size_t kbase = ((size_t)(b * H_ + h) * T_ + t) * HD_;
        float x0 = a0 * rn, x1 = a1 * rn;
        unsigned short h0 = f2bf(x0), h1 = f2bf(x1);
        khi[kbase + lane]      = h0;
        khi[kbase + lane + 64] = h1;
        klo[kbase + lane]      = f2bf(x0 - bf2f(h0));
        klo[kbase + lane + 64] = f2bf(x1 - bf2f(h1));
        if (lane == 0) beta[(size_t)(b * H_ + h) * T_ + t] = bet;
    }
}

// =====================================================================
// Kernel 2: vproj — v = beta*(x @ W_write^T); A cvt-staged, B pre-split.
// =====================================================================
__launch_bounds__(256, 2)
__global__ void vproj_kernel(const float* __restrict__ X,
                             const unsigned short* __restrict__ Wh,
                             const unsigned short* __restrict__ Wl,
                             const float* __restrict__ beta, float* __restrict__ vb) {
    extern __shared__ char gs[];
    char* AH = gs;
    char* AL = gs + 16384;
    char* BH = gs + 32768;
    char* BL = gs + 49152;
    int bm = blockIdx.x, bn = blockIdx.y;
    int tid = threadIdx.x;
    int w = tid >> 6, lr = tid & 15, lk = (tid & 63) >> 4;
    int wm = w >> 1, wn = w & 1;

    f32x4 acc[4][4];
    #pragma unroll
    for (int i = 0; i < 4; ++i)
        #pragma unroll
        for (int j = 0; j < 4; ++j) acc[i][j] = (f32x4){0.f, 0.f, 0.f, 0.f};

    for (int kt = 0; kt < 16; ++kt) {
        __syncthreads();
        #pragma unroll
        for (int q = 0; q < 8; ++q) {
            int f = tid + q * 256;
            int row = f >> 4, kq = f & 15;
            float4 av = *(const float4*)(X + (size_t)(bm * 128 + row) * D_ + kt * 64 + kq * 4);
            u16x4 ah, al;
            cvt4(av, &ah, &al);
            int off = row * 128 + ((((kq >> 1) ^ (row & 7))) << 4) + ((kq & 1) << 3);
            *(u16x4*)(AH + off) = ah; *(u16x4*)(AL + off) = al;
        }
        #pragma unroll
        for (int q = 0; q < 4; ++q) {
            int f = tid + q * 256;
            int row = f >> 3, u = f & 7;
            size_t go = (size_t)(bn * 128 + row) * D_ + kt * 64 + u * 8;
            int off = row * 128 + ((u ^ (row & 7)) << 4);
            *(u16x8*)(BH + off) = *(const u16x8*)(Wh + go);
            *(u16x8*)(BL + off) = *(const u16x8*)(Wl + go);
        }
        __syncthreads();
        #pragma unroll
        for (int ks = 0; ks < 2; ++ks) {
            bf16x8 aH[4], aL[4], bH[4], bL[4];
            #pragma unroll
            for (int mt = 0; mt < 4; ++mt) {
                int row = wm * 64 + mt * 16 + lr;
                int off = row * 128 + (((ks * 4 + lk) ^ (row & 7)) << 4);
                aH[mt] = *(const bf16x8*)(AH + off);
                aL[mt] = *(const bf16x8*)(AL + off);
            }
            #pragma unroll
            for (int nt = 0; nt < 4; ++nt) {
                int row = wn * 64 + nt * 16 + lr;
                int off = row * 128 + (((ks * 4 + lk) ^ (row & 7)) << 4);
                bH[nt] = *(const bf16x8*)(BH + off);
                bL[nt] = *(const bf16x8*)(BL + off);
            }
            #pragma unroll
            for (int mt = 0; mt < 4; ++mt)
                #pragma unroll
                for (int nt = 0; nt < 4; ++nt) {
                    acc[mt][nt] = __builtin_amdgcn_mfma_f32_16x16x32_bf16(aH[mt], bH[nt], acc[mt][nt], 0, 0, 0);
                    acc[mt][nt] = __builtin_amdgcn_mfma_f32_16x16x32_bf16(aH[mt], bL[nt], acc[mt][nt], 0, 0, 0);
                    acc[mt][nt] = __builtin_amdgcn_mfma_f32_16x16x32_bf16(aL[mt], bH[nt], acc[mt][nt], 0, 0, 0);
                }
        }
    }
    #pragma unroll
    for (int mt = 0; mt < 4; ++mt)
        #pragma unroll
        for (int r = 0; r < 4; ++r) {
            int m = bm * 128 + wm * 64 + mt * 16 + lk * 4 + r;
            int b = m >> 13, t = m & 8191;
            float bet = beta[(size_t)(b * H_ + bn) * T_ + t];
            size_t ob = ((size_t)(b * H_ + bn) * T_ + t) * HD_;
            #pragma unroll
            for (int nt = 0; nt < 4; ++nt)
                vb[ob + wn * 64 + nt * 16 + lr] = acc[mt][nt][r] * bet;
        }
}

// =====================================================================
// Kernel 3: chunk v2 — dots via MFMA (global frags), padded sm,
// inversion || kdwT overlap, kcd/v' VALU as before.
// grid 2048 x 256, dyn LDS 65792.
// =====================================================================
__launch_bounds__(256, 2)
__global__ void chunk_kernel(const unsigned short* __restrict__ khi,
                             const unsigned short* __restrict__ klo,
                             float* __restrict__ vb,
                             const float* __restrict__ beta_g,
                             const float* __restrict__ decay,
                             unsigned short* __restrict__ attn_g,
                             unsigned short* __restrict__ kcdhi_g,
                             unsigned short* __restrict__ kcdlo_g,
                             unsigned short* __restrict__ kdwh_g) {
    extern __shared__ char cs[];
    char*  sk = cs;                      // [64][128] f32 swz, 32KB (later v)
    float* sa = (float*)(cs + 32768);    // [64][64] stride 64, 16KB
    float* sm = (float*)(cs + 49152);    // [64][65] stride 65, 16640B
    __shared__ float sb[64];
    __shared__ float swgt[64];
    __shared__ float gamw[64];

    int cid = blockIdx.x;
    int bh = cid >> 7, cn = cid & 127;
    int h = bh & 7;
    int tid = threadIdx.x;
    int w = tid >> 6, l = tid & 63, lr = l & 15, lk = l >> 4;
    float dec = decay[h];
    float sg = 1.0f / (1.0f + expf(-dec));
    float lg = logf(sg);
    size_t base = (size_t)cid * 8192;

    // ---- stage k (hi+lo -> f32 swizzled LDS) ----
    #pragma unroll
    for (int lq = 0; lq < 4; ++lq) {
        int f = tid + lq * 256;
        int c = f >> 4, u0 = (f & 15) << 1;
        u16x8 hh = *(const u16x8*)(khi + base + (size_t)f * 8);
        u16x8 ll = *(const u16x8*)(klo + base + (size_t)f * 8);
        float4 v0 = {bf2f(hh[0]) + bf2f(ll[0]), bf2f(hh[1]) + bf2f(ll[1]),
                     bf2f(hh[2]) + bf2f(ll[2]), bf2f(hh[3]) + bf2f(ll[3])};
        float4 v1 = {bf2f(hh[4]) + bf2f(ll[4]), bf2f(hh[5]) + bf2f(ll[5]),
                     bf2f(hh[6]) + bf2f(ll[6]), bf2f(hh[7]) + bf2f(ll[7])};
        *r512(sk, c, u0)     = v0;
        *r512(sk, c, u0 + 1) = v1;
    }
    if (tid < 64) {
        float bv = beta_g[(size_t)bh * T_ + cn * 64 + tid];
        sb[tid] = bv;
        swgt[tid] = bv * expf((float)(tid + 1) * lg);
        gamw[tid] = expf((float)(63 - tid) * lg);
    }

    // ---- dots via MFMA: C[i][j] = k_i . k_j (A,B frags direct from global) ----
    bf16x8 aH[4], aL[4];
    #pragma unroll
    for (int ks = 0; ks < 4; ++ks) {
        size_t off = base + (size_t)(w * 16 + lr) * 128 + ks * 32 + lk * 8;
        aH[ks] = *(const bf16x8*)(khi + off);
        aL[ks] = *(const bf16x8*)(klo + off);
    }
    f32x4 dacc[4];
    #pragma unroll
    for (int nt = 0; nt < 4; ++nt) {
        bf16x8 bH[4], bL[4];
        #pragma unroll
        for (int ks = 0; ks < 4; ++ks) {
            size_t off = base + (size_t)(nt * 16 + lr) * 128 + ks * 32 + lk * 8;
            bH[ks] = *(const bf16x8*)(khi + off);
            bL[ks] = *(const bf16x8*)(klo + off);
        }
        f32x4 C = (f32x4){0.f, 0.f, 0.f, 0.f};
        #pragma unroll
        for (int ks = 0; ks < 4; ++ks) {
            C = __builtin_amdgcn_mfma_f32_16x16x32_bf16(aH[ks], bH[ks], C, 0, 0, 0);
            C = __builtin_amdgcn_mfma_f32_16x16x32_bf16(aH[ks], bL[ks], C, 0, 0, 0);
            C = __builtin_amdgcn_mfma_f32_16x16x32_bf16(aL[ks], bH[ks], C, 0, 0, 0);
        }
        dacc[nt] = C;
    }
    __syncthreads();   // sk staged + sb/swgt/gamw ready

    // ---- attn (bf16 global) + M matrix (padded sm) from dot frags ----
    size_t abase = (size_t)cid * 4096;
    #pragma unroll
    for (int nt = 0; nt < 4; ++nt)
        #pragma unroll
        for (int r = 0; r < 4; ++r) {
            int gi = w * 16 + lk * 4 + r;
            int gj = nt * 16 + lr;
            float dv = dacc[nt][r];
            float dfac = expf((float)(gi - gj) * lg);
            attn_g[abase + (size_t)gi * 64 + gj] = (gi >= gj) ? f2bf(dv * dfac) : (unsigned short)0;
            sm[gi * 65 + gj] = (gj < gi) ? sb[gi] * dv * dfac : ((gi == gj) ? 1.f : 0.f);
        }
    __syncthreads();

    // ---- inversion (wave 0) || kdwT emission (waves 2,3) ----
    if (tid < 64) {
        int j = tid;
        for (int i = 0; i < j; ++i) sa[i * 64 + j] = 0.f;
        sa[j * 64 + j] = 1.f;
        for (int i = j + 1; i < 64; ++i) {
            float s = 0.f;
            for (int p = j; p < i; ++p) s += sm[i * 65 + p] * sa[p * 64 + j];
            sa[i * 64 + j] = -s;
        }
    } else if (tid >= 128) {
        int dk = tid - 128;
        #pragma unroll
        for (int q = 0; q < 8; ++q) {
            u16x8 th;
            #pragma unroll
            for (int j = 0; j < 8; ++j) {
                int c = q * 8 + j;
                th[j] = f2bf(ld_sk(sk, c, dk) * gamw[c]);
            }
            *(u16x8*)(kdwh_g + base + (size_t)dk * 64 + q * 8) = th;
        }
    }
    __syncthreads();

    int ti = tid >> 4, te = tid & 15;
    // ---- kcd(negated) = -(A @ (k_beta * gamma^{p+1})) -> bf16 hi/lo ----
    {
        float ko[4][8] = {};
        for (int p = 0; p < 64; ++p) {
            float wq = swgt[p];
            float4 k0 = *r512(sk, p, te * 2);
            float4 k1 = *r512(sk, p, te * 2 + 1);
            float kv[8] = {k0.x, k0.y, k0.z, k0.w, k1.x, k1.y, k1.z, k1.w};
            float a0 = sa[(ti * 4 + 0) * 64 + p] * wq;
            float a1 = sa[(ti * 4 + 1) * 64 + p] * wq;
            float a2 = sa[(ti * 4 + 2) * 64 + p] * wq;
            float a3 = sa[(ti * 4 + 3) * 64 + p] * wq;
            #pragma unroll
            for (int e = 0; e < 8; ++e) {
                ko[0][e] = fmaf(a0, kv[e], ko[0][e]);
                ko[1][e] = fmaf(a1, kv[e], ko[1][e]);
                ko[2][e] = fmaf(a2, kv[e], ko[2][e]);
                ko[3][e] = fmaf(a3, kv[e], ko[3][e]);
            }
        }
        #pragma unroll
        for (int i = 0; i < 4; ++i) {
            u16x8 hh, ll;
            #pragma unroll
            for (int e = 0; e < 8; ++e) {
                float t = -ko[i][e];
                unsigned short hv = f2bf(t);
                hh[e] = hv;
                ll[e] = f2bf(t - bf2f(hv));
            }
            size_t off = base + (size_t)(ti * 4 + i) * 128 + te * 8;
            *(u16x8*)(kcdhi_g + off) = hh;
            *(u16x8*)(kcdlo_g + off) = ll;
        }
    }
    __syncthreads();

    // ---- stage v over sk ----
    #pragma unroll
    for (int lq = 0; lq < 8; ++lq) {
        int f = tid + lq * 256;
        int r = f >> 5, u = f & 31;
        *r512(sk, r, u) = ((const float4*)(vb + base))[f];
    }
    __syncthreads();

    // ---- v' = A @ v (f32, in place) ----
    {
        float vo[4][8] = {};
        for (int p = 0; p < 64; ++p) {
            float4 v0 = *r512(sk, p, te * 2);
            float4 v1 = *r512(sk, p, te * 2 + 1);
            float vv[8] = {v0.x, v0.y, v0.z, v0.w, v1.x, v1.y, v1.z, v1.w};
            float a0 = sa[(ti * 4 + 0) * 64 + p];
            float a1 = sa[(ti * 4 + 1) * 64 + p];
            float a2 = sa[(ti * 4 + 2) * 64 + p];
            float a3 = sa[(ti * 4 + 3) * 64 + p];
            #pragma unroll
            for (int e = 0; e < 8; ++e) {
                vo[0][e] = fmaf(a0, vv[e], vo[0][e]);
                vo[1][e] = fmaf(a1, vv[e], vo[1][e]);
                vo[2][e] = fmaf(a2, vv[e], vo[2][e]);
                vo[3][e] = fmaf(a3, vv[e], vo[3][e]);
            }
        }
        #pragma unroll
        for (int i = 0; i < 4; ++i) {
            float4 lo = {vo[i][0], vo[i][1], vo[i][2], vo[i][3]};
            float4 hi = {vo[i][4], vo[i][5], vo[i][6], vo[i][7]};
            size_t off = base + (size_t)(ti * 4 + i) * 128 + te * 8;
            *(float4*)(vb + off)     = lo;
            *(float4*)(vb + off + 4) = hi;
        }
    }
}

// =====================================================================
// Scan step machinery (v8 numerics; 2-prod M3, kdwh only).
// =====================================================================
#define SCAN_PREFETCH(NCH, fH, fL, atA, vnA)                                          \
    {                                                                                 \
        size_t nb = ((size_t)bh * N_ + (NCH)) * 8192;                                 \
        size_t na = ((size_t)bh * N_ + (NCH)) * 4096;                                 \
        if (grp == 0) {                                                               \
            _Pragma("unroll")                                                         \
            for (int ks = 0; ks < 4; ++ks) {                                          \
                size_t off = nb + (size_t)(cw * 16 + lr) * 128 + ks * 32 + lk * 8;    \
                fH[ks] = *(const bf16x8*)(kcdh + off);                                \
                fL[ks] = *(const bf16x8*)(kcdl + off);                                \
            }                                                                         \
            _Pragma("unroll")                                                         \
            for (int r = 0; r < 4; ++r)                                               \
                vnA[r] = vb[nb + (size_t)(cw * 16 + lk * 4 + r) * 128 + e0 + lr];     \
        } else {                                                                      \
            _Pragma("unroll")                                                         \
            for (int ks = 0; ks < 4; ++ks) {                                          \
                size_t off = nb + (size_t)(cw * 16 + lr) * 128 + ks * 32 + lk * 8;    \
                fH[ks] = *(const bf16x8*)(khi + off);                                 \
                fL[ks] = *(const bf16x8*)(klo + off);                                 \
            }                                                                         \
            _Pragma("unroll")                                                         \
            for (int ks2 = 0; ks2 < 2; ++ks2)                                         \
                atA[ks2] = *(const bf16x8*)(att + na + (size_t)(cw * 16 + lr) * 64 + ks2 * 32 + lk * 8); \
        }                                                                             \
    }

#define SCAN_STEP(CN, LIM, fH, fL, atA, vnA)                                          \
    {                                                                                 \
        size_t cb8 = ((size_t)bh * N_ + (CN)) * 8192;                                 \
        bf16x8 tH[2];                                                                 \
        _Pragma("unroll")                                                             \
        for (int ks2 = 0; ks2 < 2; ++ks2)                                             \
            tH[ks2] = *(const bf16x8*)(kdwh + cb8 + (size_t)(w * 16 + lr) * 64 + ks2 * 32 + lk * 8); \
        {                                                                             \
            u16x4 h4, l4;                                                             \
            _Pragma("unroll")                                                         \
            for (int r = 0; r < 4; ++r) {                                             \
                unsigned short hv = f2bf(Sacc[r]);                                    \
                h4[r] = hv;                                                           \
                l4[r] = f2bf(Sacc[r] - bf2f(hv));                                     \
            }                                                                         \
            int unit = 2 * w + (lk >> 1);                                             \
            int off = lr * 256 + ((unit ^ (lr & 7)) << 4) + ((lk & 1) << 3);          \
            *(u16x4*)(SH + off) = h4;                                                 \
            *(u16x4*)(SL + off) = l4;                                                 \
        }                                                                             \
        bar_lgkm();                                                                   \
        bf16x8 BH[4], BL[4];                                                          \
        _Pragma("unroll")                                                             \
        for (int ks = 0; ks < 4; ++ks) {                                              \
            int off = lr * 256 + (((ks * 4 + lk) ^ (lr & 7)) << 4);                   \
            BH[ks] = *(const bf16x8*)(SH + off);                                      \
            BL[ks] = *(const bf16x8*)(SL + off);                                      \
        }                                                                             \
        f32x4 acc1, acc2;                                                             \
        if (grp == 0) {                                                               \
            acc1 = vnA; acc2 = (f32x4){0.f, 0.f, 0.f, 0.f};                           \
            __builtin_amdgcn_s_setprio(1);                                            \
            _Pragma("unroll")                                                         \
            for (int ks = 0; ks < 2; ++ks) {                                          \
                acc1 = __builtin_amdgcn_mfma_f32_16x16x32_bf16(fH[ks], BH[ks], acc1, 0, 0, 0);       \
                acc2 = __builtin_amdgcn_mfma_f32_16x16x32_bf16(fH[ks+2], BH[ks+2], acc2, 0, 0, 0);   \
                acc1 = __builtin_amdgcn_mfma_f32_16x16x32_bf16(fH[ks], BL[ks], acc1, 0, 0, 0);       \
                acc2 = __builtin_amdgcn_mfma_f32_16x16x32_bf16(fH[ks+2], BL[ks+2], acc2, 0, 0, 0);   \
                acc1 = __builtin_amdgcn_mfma_f32_16x16x32_bf16(fL[ks], BH[ks], acc1, 0, 0, 0);       \
                acc2 = __builtin_amdgcn_mfma_f32_16x16x32_bf16(fL[ks+2], BH[ks+2], acc2, 0, 0, 0);   \
            }                                                                         \
            __builtin_amdgcn_s_setprio(0);                                            \
            u16x4 h4, l4;                                                             \
            _Pragma("unroll")                                                         \
            for (int r = 0; r < 4; ++r) {                                             \
                float vv = acc1[r] + acc2[r];                                         \
                unsigned short hv = f2bf(vv);                                         \
                h4[r] = hv; l4[r] = f2bf(vv - bf2f(hv));                              \
            }                                                                         \
            int cu = 2 * cw + (lk >> 1);                                              \
            int off = lr * 128 + ((cu ^ (lr & 7)) << 4) + ((lk & 1) << 3);            \
            *(u16x4*)(VH + off) = h4;  *(u16x4*)(VL + off) = l4;                      \
        } else {                                                                      \
            acc1 = (f32x4){0.f, 0.f, 0.f, 0.f}; acc2 = acc1;                          \
            __builtin_amdgcn_s_setprio(1);                                            \
            _Pragma("unroll")                                                         \
            for (int ks = 0; ks < 2; ++ks) {                                          \
                acc1 = __builtin_amdgcn_mfma_f32_16x16x32_bf16(fH[ks], BH[ks], acc1, 0, 0, 0);       \
                acc2 = __builtin_amdgcn_mfma_f32_16x16x32_bf16(fH[ks+2], BH[ks+2], acc2, 0, 0, 0);   \
                acc1 = __builtin_amdgcn_mfma_f32_16x16x32_bf16(fH[ks], BL[ks], acc1, 0, 0, 0);       \
                acc2 = __builtin_amdgcn_mfma_f32_16x16x32_bf16(fH[ks+2], BL[ks+2], acc2, 0, 0, 0);   \
                acc1 = __builtin_amdgcn_mfma_f32_16x16x32_bf16(fL[ks], BH[ks], acc1, 0, 0, 0);       \
                acc2 = __builtin_amdgcn_mfma_f32_16x16x32_bf16(fL[ks+2], BH[ks+2], acc2, 0, 0, 0);   \
            }                                                                         \
            __builtin_amdgcn_s_setprio(0);                                            \
        }                                                                             \
        bar_lgkm();                                                                   \
        bf16x8 VHf[2], VLf[2];                                                        \
        _Pragma("unroll")                                                             \
        for (int ks2 = 0; ks2 < 2; ++ks2) {                                           \
            int off = lr * 128 + (((ks2 * 4 + lk) ^ (lr & 7)) << 4);                  \
            VHf[ks2] = *(const bf16x8*)(VH + off);                                    \
            VLf[ks2] = *(const bf16x8*)(VL + off);                                    \
        }                                                                             \
        if (grp == 1) {                                                               \
            f32x4 om;                                                                 \
            _Pragma("unroll")                                                         \
            for (int r = 0; r < 4; ++r) om[r] = (acc1[r] + acc2[r]) * dev4[r];        \
            _Pragma("unroll")                                                         \
            for (int ks2 = 0; ks2 < 2; ++ks2) {                                       \
                om = __builtin_amdgcn_mfma_f32_16x16x32_bf16(atA[ks2], VHf[ks2], om, 0, 0, 0);  \
                om = __builtin_amdgcn_mfma_f32_16x16x32_bf16(atA[ks2], VLf[ks2], om, 0, 0, 0);  \
            }                                                                         \
            _Pragma("unroll")                                                         \
            for (int r = 0; r < 4; ++r)                                               \
                vb[cb8 + (size_t)(cw * 16 + lk * 4 + r) * 128 + e0 + lr] = om[r];     \
        }                                                                             \
        if ((CN) + 2 < (LIM)) SCAN_PREFETCH((CN) + 2, fH, fL, atA, vnA)               \
        {                                                                             \
            _Pragma("unroll")                                                         \
            for (int r = 0; r < 4; ++r) Sacc[r] *= g64;                               \
            f32x4 tmp = (f32x4){0.f, 0.f, 0.f, 0.f};                                  \
            __builtin_amdgcn_s_setprio(1);                                            \
            Sacc = __builtin_amdgcn_mfma_f32_16x16x32_bf16(tH[0], VHf[0], Sacc, 0, 0, 0);  \
            tmp  = __builtin_amdgcn_mfma_f32_16x16x32_bf16(tH[1], VHf[1], tmp,  0, 0, 0);  \
            Sacc = __builtin_amdgcn_mfma_f32_16x16x32_bf16(tH[0], VLf[0], Sacc, 0, 0, 0);  \
            tmp  = __builtin_amdgcn_mfma_f32_16x16x32_bf16(tH[1], VLf[1], tmp,  0, 0, 0);  \
            __builtin_amdgcn_s_setprio(0);                                            \
            _Pragma("unroll")                                                         \
            for (int r = 0; r < 4; ++r) Sacc[r] += tmp[r];                            \
        }                                                                             \
    }

// =====================================================================
// Kernel 4: scan (sequential v8, proven) — 128-chunk scan, o in place.
// grid 128 = 16 bh x 8 e-strips(16), 512 thr.
// =====================================================================
__launch_bounds__(512, 1)
__global__ void scan_kernel(const unsigned short* __restrict__ khi,
                            const unsigned short* __restrict__ klo,
                            float* __restrict__ vb,
                            const unsigned short* __restrict__ kcdh,
                            const unsigned short* __restrict__ kcdl,
                            const unsigned short* __restrict__ att,
                            const unsigned short* __restrict__ kdwh,
                            const float* __restrict__ decay) {
    __shared__ char SH[4096];
    __shared__ char SL[4096];
    __shared__ char VH[2048];
    __shared__ char VL[2048];

    int bid = blockIdx.x;
    int bh = ((bid >> 6) << 3) + (bid & 7);
    int strip = (bid >> 3) & 7;
    int e0 = strip * 16;
    int tid = threadIdx.x;
    int w = tid >> 6, l = tid & 63, lr = l & 15, lk = l >> 4;
    int grp = w >> 2, cw = w & 3;
    float dec = decay[bh & 7];
    float sg = 1.0f / (1.0f + expf(-dec));
    float lg = logf(sg);
    float g64 = expf(64.f * lg);
    float dev4[4];
    #pragma unroll
    for (int r = 0; r < 4; ++r)
        dev4[r] = expf((float)(cw * 16 + lk * 4 + r + 1) * lg);

    f32x4 Sacc = (f32x4){0.f, 0.f, 0.f, 0.f};
    bf16x8 fHa[4], fLa[4], atAa[2];
    bf16x8 fHb[4], fLb[4], atAb[2];
    f32x4 vnAa, vnAb;

    SCAN_PREFETCH(0, fHa, fLa, atAa, vnAa)
    SCAN_PREFETCH(1, fHb, fLb, atAb, vnAb)
    for (int cn = 0; cn < N_; cn += 2) {
        SCAN_STEP(cn,     N_, fHa, fLa, atAa, vnAa)
        SCAN_STEP(cn + 1, N_, fHb, fLb, atAb, vnAb)
    }
}

// =====================================================================
// Kernel 5: final — out = x + o @ W_read^T. A = o f32 (cvt), B pre-split.
// =====================================================================
__launch_bounds__(256, 2)
__global__ void final_kernel(const float* __restrict__ X,
                             const unsigned short* __restrict__ Wh,
                             const unsigned short* __restrict__ Wl,
                             const float* __restrict__ OB, float* __restrict__ out) {
    extern __shared__ char gs[];
    char* AH = gs;
    char* AL = gs + 16384;
    char* BH = gs + 32768;
    char* BL = gs + 49152;
    int bm = blockIdx.x, bn = blockIdx.y;
    int tid = threadIdx.x;
    int w = tid >> 6, lr = tid & 15, lk = (tid & 63) >> 4;
    int wm = w >> 1, wn = w & 1;

    f32x4 acc[4][4];
    #pragma unroll
    for (int i = 0; i < 4; ++i)
        #pragma unroll
        for (int j = 0; j < 4; ++j) acc[i][j] = (f32x4){0.f, 0.f, 0.f, 0.f};

    for (int kt = 0; kt < 16; ++kt) {
        int hh = kt >> 1, e0g = (kt & 1) * 64;
        __syncthreads();
        #pragma unroll
        for (int q = 0; q < 8; ++q) {
            int f = tid + q * 256;
            int row = f >> 4, kq = f & 15;
            int m = bm * 128 + row;
            int b = m >> 13, t = m & 8191;
            float4 av = *(const float4*)(OB + (((size_t)(b * H_ + hh) * T_ + t) << 7) + e0g + kq * 4);
            u16x4 ah, al;
            cvt4(av, &ah, &al);
            int off = row * 128 + ((((kq >> 1) ^ (row & 7))) << 4) + ((kq & 1) << 3);
            *(u16x4*)(AH + off) = ah; *(u16x4*)(AL + off) = al;
        }
        #pragma unroll
        for (int q = 0; q < 4; ++q) {
            int f = tid + q * 256;
            int row = f >> 3, u = f & 7;
            size_t go = (size_t)(bn * 128 + row) * D_ + kt * 64 + u * 8;
            int off = row * 128 + ((u ^ (row & 7)) << 4);
            *(u16x8*)(BH + off) = *(const u16x8*)(Wh + go);
            *(u16x8*)(BL + off) = *(const u16x8*)(Wl + go);
        }
        __syncthreads();
        #pragma unroll
        for (int ks = 0; ks < 2; ++ks) {
            bf16x8 aH[4], aL[4], bH[4], bL[4];
            #pragma unroll
            for (int mt = 0; mt < 4; ++mt) {
                int row = wm * 64 + mt * 16 + lr;
                int off = row * 128 + (((ks * 4 + lk) ^ (row & 7)) << 4);
                aH[mt] = *(const bf16x8*)(AH + off);
                aL[mt] = *(const bf16x8*)(AL + off);
            }
            #pragma unroll
            for (int nt = 0; nt < 4; ++nt) {
                int row = wn * 64 + nt * 16 + lr;
                int off = row * 128 + (((ks * 4 + lk) ^ (row & 7)) << 4);
                bH[nt] = *(const bf16x8*)(BH + off);
                bL[nt] = *(const bf16x8*)(BL + off);
            }
            #pragma unroll
            for (int mt = 0; mt < 4; ++mt)
                #pragma unroll
                for (int nt = 0; nt < 4; ++nt) {
                    acc[mt][nt] = __builtin_amdgcn_mfma_f32_16x16x32_bf16(aH[mt], bH[nt], acc[mt][nt], 0, 0, 0);
                    acc[mt][nt] = __builtin_amdgcn_mfma_f32_16x16x32_bf16(aH[mt], bL[nt], acc[mt][nt], 0, 0, 0);
                    acc[mt][nt] = __builtin_amdgcn_mfma_f32_16x16x32_bf16(aL[mt], bH[nt], acc[mt][nt], 0, 0, 0);
                }
        }
    }
    #pragma unroll
    for (int mt = 0; mt < 4; ++mt)
        #pragma unroll
        for (int r = 0; r < 4; ++r) {
            int m = bm * 128 + wm * 64 + mt * 16 + lk * 4 + r;
            size_t xo = (size_t)m * D_ + bn * 128;
            #pragma unroll
            for (int nt = 0; nt < 4; ++nt) {
                int n = wn * 64 + nt * 16 + lr;
                out[xo + n] = X[xo + n] + acc[mt][nt][r];
            }
        }
}

// =====================================================================
extern "C" void kernel_launch(void* const* d_in, const int* in_sizes, int n_in,
                              void* d_out, int out_size, void* d_ws, size_t ws_size,
                              hipStream_t stream) {
    const float* X   = (const float*)d_in[0];
    const float* Ww  = (const float*)d_in[1];
    const float* Wr  = (const float*)d_in[2];
    const float* Wb  = (const float*)d_in[3];
    const float* dec = (const float*)d_in[4];

    // workspace layout (bytes). Total 252,182,528 (proven).
    char* ws = (char*)d_ws;
    unsigned short* khi  = (unsigned short*)(ws);                 // 32MB [c][dk] hi
    unsigned short* klo  = (unsigned short*)(ws + 33554432);      // 32MB
    float*          vb   = (float*)(ws + 67108864);               // 64MB  v -> v' -> o (f32)
    unsigned short* kcdh = (unsigned short*)(ws + 134217728);     // 32MB
    unsigned short* kcdl = (unsigned short*)(ws + 167772160);     // 32MB
    unsigned short* attn = (unsigned short*)(ws + 201326592);     // 16MB
    float*          beta = (float*)(ws + 218103808);              // 0.5MB
    unsigned short* kdwh = (unsigned short*)(ws + 218628096);     // 32MB [dk][c]*gamma hi
    if (ws_size < 252182528ull) return;

    // Transient weight-split regions (in dead buffers at time of use).
    unsigned short* Wwh = (unsigned short*)(ws + 134217728);      // kcd region, pre-chunk
    unsigned short* Wwl = (unsigned short*)(ws + 136314880);
    unsigned short* Wrh = (unsigned short*)(ws + 201326592);      // attn region, post-scan
    unsigned short* Wrl = (unsigned short*)(ws + 203423744);

    hipFuncSetAttribute((const void*)vproj_kernel, hipFuncAttributeMaxDynamicSharedMemorySize, 65536);
    hipFuncSetAttribute((const void*)chunk_kernel, hipFuncAttributeMaxDynamicSharedMemorySize, 65792);
    hipFuncSetAttribute((const void*)final_kernel, hipFuncAttributeMaxDynamicSharedMemorySize, 65536);

    hipLaunchKernelGGL(prep_kernel, dim3(B_ * T_), dim3(256), 0, stream, X, Wb, khi, klo, beta);
    hipLaunchKernelGGL(split_kernel, dim3(512), dim3(256), 0, stream, Ww, Wwh, Wwl);
    hipLaunchKernelGGL(vproj_kernel, dim3(128, 8), dim3(256), 65536, stream, X, Wwh, Wwl, beta, vb);
    hipLaunchKernelGGL(chunk_kernel, dim3(B_ * H_ * N_), dim3(256), 65792, stream,
                       khi, klo, vb, beta, dec, attn, kcdh, kcdl, kdwh);
    hipLaunchKernelGGL(scan_kernel, dim3(128), dim3(512), 0, stream,
                       khi, klo, vb, kcdh, kcdl, attn, kdwh, dec);
    hipLaunchKernelGGL(split_kernel, dim3(512), dim3(256), 0, stream, Wr, Wrh, Wrl);
    hipLaunchKernelGGL(final_kernel, dim3(128, 8), dim3(256), 65536, stream, X, Wrh, Wrl, vb, (float*)d_out);
}